// Round 2
// baseline (289.949 us; speedup 1.0000x reference)
//
#include <hip/hip_runtime.h>

#define C_SEG 4096
#define E_CH 16
#define NE_EDGES 16384
#define P_PIX (1024 * 1024)
#define SCALE 262144.0f        // 2^18 fixed-point scale
#define INV_SCALE (1.0f / 262144.0f)

// ws layout (4-byte elems):
//   [0,      65536)  sums_i[C][E]   (int, scaled by 2^18)
//   [65536,  69632)  counts_i[C]    (int)
//   [69632, 135168)  means[C][E]    (float)
//   [135168,139264)  inv_n[C]       (float)
//   [139264,140288)  partials_intra[1024]
//   [140288,140352)  partials_inter[64]

// ---------------------------------------------------------------------------
// Kernel 1: segment sums + counts, LDS-privatized, INTEGER atomics (native
// ds_add_u32 — fp32 atomicAdd on LDS lowers to a CAS loop, ~170+ cyc/op).
// grid = (64 pixel chunks, 5 groups). group 0: counts; group g in 1..4:
// channels (g-1)*4 .. (g-1)*4+3. Chunk = 16384 pixels.
// Bin layout [c][s]: bank = s % 32 (random) instead of [s][c] (8 banks).
// ---------------------------------------------------------------------------
__global__ __launch_bounds__(256) void k_segsum(const float* __restrict__ emb,
                                                const int* __restrict__ seg,
                                                int* __restrict__ sums_i,
                                                int* __restrict__ counts_i) {
    __shared__ int bins[C_SEG * 4];  // 64 KB
    const int g = blockIdx.y;
    const int t = threadIdx.x;
    const int base = blockIdx.x * 16384;

    for (int i = t; i < C_SEG * 4; i += 256) bins[i] = 0;
    __syncthreads();

    if (g == 0) {
        for (int it = 0; it < 16; ++it) {
            const int idx = base + (it * 256 + t) * 4;
            const int4 s4 = *(const int4*)(seg + idx);
            atomicAdd(&bins[s4.x], 1);
            atomicAdd(&bins[s4.y], 1);
            atomicAdd(&bins[s4.z], 1);
            atomicAdd(&bins[s4.w], 1);
        }
        __syncthreads();
        for (int i = t; i < C_SEG; i += 256) {
            const int v = bins[i];
            if (v != 0) atomicAdd(&counts_i[i], v);
        }
    } else {
        const int c0 = (g - 1) * 4;
        for (int it = 0; it < 16; ++it) {
            const int idx = base + (it * 256 + t) * 4;
            const int4 s4 = *(const int4*)(seg + idx);
#pragma unroll
            for (int c = 0; c < 4; ++c) {
                const float4 v =
                    *(const float4*)(emb + (size_t)(c0 + c) * P_PIX + idx);
                atomicAdd(&bins[c * C_SEG + s4.x], __float2int_rn(v.x * SCALE));
                atomicAdd(&bins[c * C_SEG + s4.y], __float2int_rn(v.y * SCALE));
                atomicAdd(&bins[c * C_SEG + s4.z], __float2int_rn(v.z * SCALE));
                atomicAdd(&bins[c * C_SEG + s4.w], __float2int_rn(v.w * SCALE));
            }
        }
        __syncthreads();
        for (int i = t; i < C_SEG * 4; i += 256) {
            const int c = i >> 12, s = i & (C_SEG - 1);
            const int v = bins[i];
            if (v != 0) atomicAdd(&sums_i[s * E_CH + c0 + c], v);
        }
    }
}

// ---------------------------------------------------------------------------
// Kernel 2: means = (sums_i/SCALE) / max(count,1); inv_n = 1/max(count,1)
// ---------------------------------------------------------------------------
__global__ __launch_bounds__(256) void k_means(const int* __restrict__ sums_i,
                                               const int* __restrict__ counts_i,
                                               float* __restrict__ means,
                                               float* __restrict__ inv_n) {
    const int i = blockIdx.x * 256 + threadIdx.x;  // 65536 total
    const int c = i >> 4;
    const float n = fmaxf((float)counts_i[c], 1.0f);
    means[i] = (float)sums_i[i] * INV_SCALE / n;
    if ((i & 15) == 0) inv_n[c] = 1.0f / n;
}

__device__ __forceinline__ float block_reduce(float v) {
    for (int o = 32; o > 0; o >>= 1) v += __shfl_down(v, o, 64);
    __shared__ float wsum[4];
    const int t = threadIdx.x;
    if ((t & 63) == 0) wsum[t >> 6] = v;
    __syncthreads();
    return wsum[0] + wsum[1] + wsum[2] + wsum[3];
}

// ---------------------------------------------------------------------------
// Kernel 3: intra term. 4 pixels/thread (float4), 1024 blocks x 256.
// Writes one pre-scaled partial per block (no same-address atomics).
// ---------------------------------------------------------------------------
__global__ __launch_bounds__(256) void k_intra(const float* __restrict__ emb,
                                               const int* __restrict__ seg,
                                               const float* __restrict__ means,
                                               const float* __restrict__ inv_n,
                                               float* __restrict__ partials) {
    const int q = blockIdx.x * 256 + threadIdx.x;  // quad index, 262144 total
    const int4 s4 = *(const int4*)(seg + q * 4);
    const float4* emb4 = (const float4*)emb;

    float mA[16], mB[16], mC[16], mD[16];
#pragma unroll
    for (int j = 0; j < 4; ++j) {
        ((float4*)mA)[j] = ((const float4*)(means + s4.x * E_CH))[j];
        ((float4*)mB)[j] = ((const float4*)(means + s4.y * E_CH))[j];
        ((float4*)mC)[j] = ((const float4*)(means + s4.z * E_CH))[j];
        ((float4*)mD)[j] = ((const float4*)(means + s4.w * E_CH))[j];
    }

    float dx = 0.f, dy = 0.f, dz = 0.f, dw = 0.f;
#pragma unroll
    for (int c = 0; c < 16; ++c) {
        const float4 e = emb4[(size_t)c * (P_PIX / 4) + q];
        dx = fmaf(e.x, mA[c], dx);
        dy = fmaf(e.y, mB[c], dy);
        dz = fmaf(e.z, mC[c], dz);
        dw = fmaf(e.w, mD[c], dw);
    }

    float v = fmaxf(0.5f - dx, 0.0f) * inv_n[s4.x]   // 1 - dot - 0.5 = 0.5 - dot
            + fmaxf(0.5f - dy, 0.0f) * inv_n[s4.y]
            + fmaxf(0.5f - dz, 0.0f) * inv_n[s4.z]
            + fmaxf(0.5f - dw, 0.0f) * inv_n[s4.w];

    const float b = block_reduce(v);
    if (threadIdx.x == 0) partials[blockIdx.x] = b * (1.0f / (float)C_SEG);
}

// ---------------------------------------------------------------------------
// Kernel 4: inter term. 1 thread per edge, 64 blocks x 256.
// ---------------------------------------------------------------------------
__global__ __launch_bounds__(256) void k_inter(const int* __restrict__ edges,
                                               const float* __restrict__ w,
                                               const float* __restrict__ means,
                                               float* __restrict__ partials) {
    const int i = blockIdx.x * 256 + threadIdx.x;  // 16384 total
    const int u = edges[i];
    const int v = edges[NE_EDGES + i];
    const float4* mu = (const float4*)(means + u * E_CH);
    const float4* mv = (const float4*)(means + v * E_CH);
    float dot = 0.0f;
#pragma unroll
    for (int j = 0; j < 4; ++j) {
        const float4 a = mu[j];
        const float4 b = mv[j];
        dot = fmaf(a.x, b.x, dot);
        dot = fmaf(a.y, b.y, dot);
        dot = fmaf(a.z, b.z, dot);
        dot = fmaf(a.w, b.w, dot);
    }
    const float val = fmaxf(1.5f - (1.0f - dot) * w[i], 0.0f);
    const float b = block_reduce(val);
    if (threadIdx.x == 0) partials[blockIdx.x] = b * (1.0f / (float)NE_EDGES);
}

// ---------------------------------------------------------------------------
// Kernel 5: final reduction of 1024 + 64 partials, writes the scalar.
// ---------------------------------------------------------------------------
__global__ __launch_bounds__(256) void k_final(const float* __restrict__ parts,
                                               float* __restrict__ out) {
    float v = 0.0f;
    for (int i = threadIdx.x; i < 1024 + 64; i += 256) v += parts[i];
    const float b = block_reduce(v);
    if (threadIdx.x == 0) out[0] = b;
}

extern "C" void kernel_launch(void* const* d_in, const int* in_sizes, int n_in,
                              void* d_out, int out_size, void* d_ws,
                              size_t ws_size, hipStream_t stream) {
    const float* emb = (const float*)d_in[0];      // (1,16,1024,1024) fp32
    const float* weights = (const float*)d_in[1];  // (16384,) fp32
    const int* seg = (const int*)d_in[2];          // (1,1,1024,1024) int32
    const int* edges = (const int*)d_in[3];        // (2,16384) int32
    float* out = (float*)d_out;

    char* ws = (char*)d_ws;
    int* sums_i = (int*)ws;                         // 65536
    int* counts_i = (int*)(ws + 65536 * 4);         // 4096
    float* means = (float*)(ws + 69632 * 4);        // 65536
    float* invn = (float*)(ws + 135168 * 4);        // 4096
    float* partials = (float*)(ws + 139264 * 4);    // 1024 intra + 64 inter

    hipMemsetAsync(sums_i, 0, (65536 + 4096) * sizeof(int), stream);

    dim3 g1(64, 5);
    k_segsum<<<g1, 256, 0, stream>>>(emb, seg, sums_i, counts_i);
    k_means<<<256, 256, 0, stream>>>(sums_i, counts_i, means, invn);
    k_intra<<<1024, 256, 0, stream>>>(emb, seg, means, invn, partials);
    k_inter<<<64, 256, 0, stream>>>(edges, weights, means, partials + 1024);
    k_final<<<1, 256, 0, stream>>>(partials, out);
}

// Round 3
// 136.537 us; speedup vs baseline: 2.1236x; 2.1236x over previous
//
#include <hip/hip_runtime.h>

#define C_SEG 4096
#define E_CH 16
#define NE_EDGES 16384
#define P_PIX (1024 * 1024)
#define N_CHUNK 32
#define SCALE 262144.0f        // 2^18 fixed point
#define INV_SCALE (1.0f / 262144.0f)

// ws layout (byte offsets):
//   0        means[4096][16]           256 KB
//   0x40000  inv_n[4096]                16 KB
//   0x44000  partials_intra[1024]        4 KB
//   0x45000  partials_inter[64]        256 B
//   0x46000  sums_i[4096][16] (int)    256 KB   } fallback path only
//   0x86000  counts_i[4096]  (int)      16 KB   }
//   0x8A000  sums_part[16][32][4096]     8 MB   } partials path
//   0x88A000 cnt_part[32][4096]        512 KB   }
#define WS_NEED 0x90A000

// ---------------------------------------------------------------------------
// k_segsum: grid (N_CHUNK, 17), block 512. One channel per block (g<16),
// g==16 does counts. 16 KB LDS bins -> ~17 waves/CU (vs R2's 5) so the
// ~350-cycle LDS-atomic latency is hidden by TLP. Merge = plain partial
// stores (no global atomics -> no write-through amplification).
// ---------------------------------------------------------------------------
__global__ __launch_bounds__(512) void k_segsum(const float* __restrict__ emb,
                                                const int* __restrict__ seg,
                                                float* __restrict__ sums_part,
                                                float* __restrict__ cnt_part,
                                                int* __restrict__ sums_i,
                                                int* __restrict__ counts_i,
                                                int use_partials) {
    __shared__ int bins[C_SEG];  // 16 KB
    const int chunk = blockIdx.x;
    const int g = blockIdx.y;
    const int t = threadIdx.x;
    const int base = chunk * (P_PIX / N_CHUNK);  // 32768 pixels per chunk

    for (int i = t; i < C_SEG; i += 512) bins[i] = 0;
    __syncthreads();

    if (g == 16) {
        // counts histogram
        for (int it = 0; it < 16; ++it) {
            const int idx = base + (it * 512 + t) * 4;
            const int4 s4 = *(const int4*)(seg + idx);
            atomicAdd(&bins[s4.x], 1);
            atomicAdd(&bins[s4.y], 1);
            atomicAdd(&bins[s4.z], 1);
            atomicAdd(&bins[s4.w], 1);
        }
        __syncthreads();
        if (use_partials) {
            for (int i = t; i < C_SEG; i += 512)
                cnt_part[chunk * C_SEG + i] = (float)bins[i];
        } else {
            for (int i = t; i < C_SEG; i += 512) {
                const int v = bins[i];
                if (v) atomicAdd(&counts_i[i], v);
            }
        }
    } else {
        const float* ec = emb + (size_t)g * P_PIX;
        for (int it = 0; it < 16; ++it) {
            const int idx = base + (it * 512 + t) * 4;
            const int4 s4 = *(const int4*)(seg + idx);
            const float4 v = *(const float4*)(ec + idx);
            atomicAdd(&bins[s4.x], __float2int_rn(v.x * SCALE));
            atomicAdd(&bins[s4.y], __float2int_rn(v.y * SCALE));
            atomicAdd(&bins[s4.z], __float2int_rn(v.z * SCALE));
            atomicAdd(&bins[s4.w], __float2int_rn(v.w * SCALE));
        }
        __syncthreads();
        if (use_partials) {
            float* dst = sums_part + ((size_t)g * N_CHUNK + chunk) * C_SEG;
            for (int i = t; i < C_SEG; i += 512)
                dst[i] = (float)bins[i] * INV_SCALE;
        } else {
            for (int i = t; i < C_SEG; i += 512) {
                const int v = bins[i];
                if (v) atomicAdd(&sums_i[i * E_CH + g], v);
            }
        }
    }
}

// ---------------------------------------------------------------------------
// k_means: 256 blocks x 256 thr, 16 segs per block. Reduces chunk partials
// (or reads merged ints in fallback), writes means[s][c] + inv_n[s].
// ---------------------------------------------------------------------------
__global__ __launch_bounds__(256) void k_means(const float* __restrict__ sums_part,
                                               const float* __restrict__ cnt_part,
                                               const int* __restrict__ sums_i,
                                               const int* __restrict__ counts_i,
                                               float* __restrict__ means,
                                               float* __restrict__ inv_n,
                                               int use_partials) {
    const int t = threadIdx.x, b = blockIdx.x;
    if (use_partials) {
        __shared__ float cpart[16][16];
        __shared__ float n_sh[16];
        {
            const int kk = t >> 4, sl = t & 15;
            const int s = b * 16 + sl;
            cpart[kk][sl] = cnt_part[(kk * 2) * C_SEG + s] +
                            cnt_part[(kk * 2 + 1) * C_SEG + s];
        }
        __syncthreads();
        if (t < 16) {
            float n = 0.0f;
#pragma unroll
            for (int j = 0; j < 16; ++j) n += cpart[j][t];
            n = fmaxf(n, 1.0f);
            n_sh[t] = n;
            inv_n[b * 16 + t] = 1.0f / n;
        }
        __syncthreads();
        const int c = t >> 4, sl = t & 15;
        const int s = b * 16 + sl;
        float acc = 0.0f;
#pragma unroll
        for (int k = 0; k < N_CHUNK; ++k)
            acc += sums_part[((size_t)c * N_CHUNK + k) * C_SEG + s];
        means[s * E_CH + c] = acc / n_sh[sl];
    } else {
        const int c = t >> 4, sl = t & 15;
        const int s = b * 16 + sl;
        const float n = fmaxf((float)counts_i[s], 1.0f);
        means[s * E_CH + c] = (float)sums_i[s * E_CH + c] * INV_SCALE / n;
        if (t < 16) inv_n[b * 16 + t] = 1.0f / fmaxf((float)counts_i[b * 16 + t], 1.0f);
    }
}

__device__ __forceinline__ float block_reduce(float v) {
    for (int o = 32; o > 0; o >>= 1) v += __shfl_down(v, o, 64);
    __shared__ float wsum[4];
    const int t = threadIdx.x;
    if ((t & 63) == 0) wsum[t >> 6] = v;
    __syncthreads();
    return wsum[0] + wsum[1] + wsum[2] + wsum[3];
}

// ---------------------------------------------------------------------------
// k_intra: 4 pixels/thread (float4), 1024 blocks x 256, per-block partials.
// ---------------------------------------------------------------------------
__global__ __launch_bounds__(256) void k_intra(const float* __restrict__ emb,
                                               const int* __restrict__ seg,
                                               const float* __restrict__ means,
                                               const float* __restrict__ inv_n,
                                               float* __restrict__ partials) {
    const int q = blockIdx.x * 256 + threadIdx.x;  // quad index
    const int4 s4 = *(const int4*)(seg + q * 4);
    const float4* emb4 = (const float4*)emb;

    float mA[16], mB[16], mC[16], mD[16];
#pragma unroll
    for (int j = 0; j < 4; ++j) {
        ((float4*)mA)[j] = ((const float4*)(means + s4.x * E_CH))[j];
        ((float4*)mB)[j] = ((const float4*)(means + s4.y * E_CH))[j];
        ((float4*)mC)[j] = ((const float4*)(means + s4.z * E_CH))[j];
        ((float4*)mD)[j] = ((const float4*)(means + s4.w * E_CH))[j];
    }

    float dx = 0.f, dy = 0.f, dz = 0.f, dw = 0.f;
#pragma unroll
    for (int c = 0; c < 16; ++c) {
        const float4 e = emb4[(size_t)c * (P_PIX / 4) + q];
        dx = fmaf(e.x, mA[c], dx);
        dy = fmaf(e.y, mB[c], dy);
        dz = fmaf(e.z, mC[c], dz);
        dw = fmaf(e.w, mD[c], dw);
    }

    const float v = fmaxf(0.5f - dx, 0.0f) * inv_n[s4.x]
                  + fmaxf(0.5f - dy, 0.0f) * inv_n[s4.y]
                  + fmaxf(0.5f - dz, 0.0f) * inv_n[s4.z]
                  + fmaxf(0.5f - dw, 0.0f) * inv_n[s4.w];

    const float b = block_reduce(v);
    if (threadIdx.x == 0) partials[blockIdx.x] = b * (1.0f / (float)C_SEG);
}

// ---------------------------------------------------------------------------
// k_inter: 1 thread per edge, 64 blocks x 256.
// ---------------------------------------------------------------------------
__global__ __launch_bounds__(256) void k_inter(const int* __restrict__ edges,
                                               const float* __restrict__ w,
                                               const float* __restrict__ means,
                                               float* __restrict__ partials) {
    const int i = blockIdx.x * 256 + threadIdx.x;
    const int u = edges[i];
    const int v = edges[NE_EDGES + i];
    const float4* mu = (const float4*)(means + u * E_CH);
    const float4* mv = (const float4*)(means + v * E_CH);
    float dot = 0.0f;
#pragma unroll
    for (int j = 0; j < 4; ++j) {
        const float4 a = mu[j];
        const float4 b = mv[j];
        dot = fmaf(a.x, b.x, dot);
        dot = fmaf(a.y, b.y, dot);
        dot = fmaf(a.z, b.z, dot);
        dot = fmaf(a.w, b.w, dot);
    }
    const float val = fmaxf(1.5f - (1.0f - dot) * w[i], 0.0f);
    const float b = block_reduce(val);
    if (threadIdx.x == 0) partials[blockIdx.x] = b * (1.0f / (float)NE_EDGES);
}

// ---------------------------------------------------------------------------
// k_final: sum 1024 + 64 partials.
// ---------------------------------------------------------------------------
__global__ __launch_bounds__(256) void k_final(const float* __restrict__ parts,
                                               float* __restrict__ out) {
    float v = 0.0f;
    for (int i = threadIdx.x; i < 1024 + 64; i += 256) v += parts[i];
    const float b = block_reduce(v);
    if (threadIdx.x == 0) out[0] = b;
}

extern "C" void kernel_launch(void* const* d_in, const int* in_sizes, int n_in,
                              void* d_out, int out_size, void* d_ws,
                              size_t ws_size, hipStream_t stream) {
    const float* emb = (const float*)d_in[0];      // (1,16,1024,1024) fp32
    const float* weights = (const float*)d_in[1];  // (16384,) fp32
    const int* seg = (const int*)d_in[2];          // (1,1,1024,1024) int32
    const int* edges = (const int*)d_in[3];        // (2,16384) int32
    float* out = (float*)d_out;

    char* ws = (char*)d_ws;
    float* means = (float*)(ws);
    float* invn = (float*)(ws + 0x40000);
    float* part_intra = (float*)(ws + 0x44000);
    float* part_inter = (float*)(ws + 0x45000);
    int* sums_i = (int*)(ws + 0x46000);
    int* counts_i = (int*)(ws + 0x86000);
    float* sums_part = (float*)(ws + 0x8A000);
    float* cnt_part = (float*)(ws + 0x88A000);

    const int use_partials = (ws_size >= (size_t)WS_NEED) ? 1 : 0;
    if (!use_partials) {
        hipMemsetAsync(sums_i, 0, (65536 + 4096) * sizeof(int), stream);
    }

    dim3 g1(N_CHUNK, 17);
    k_segsum<<<g1, 512, 0, stream>>>(emb, seg, sums_part, cnt_part, sums_i,
                                     counts_i, use_partials);
    k_means<<<256, 256, 0, stream>>>(sums_part, cnt_part, sums_i, counts_i,
                                     means, invn, use_partials);
    k_intra<<<1024, 256, 0, stream>>>(emb, seg, means, invn, part_intra);
    k_inter<<<64, 256, 0, stream>>>(edges, weights, means, part_inter);
    k_final<<<1, 256, 0, stream>>>(part_intra, out);
}